// Round 1
// baseline (131.162 us; speedup 1.0000x reference)
//
#include <hip/hip_runtime.h>
#include <hip/hip_bf16.h>

#define B_    128
#define N_    4096
#define DIM_  16
#define HID_  128
#define NT_   4             // grid.x tiles -> 512 blocks, 2 resident/CU
#define ROWS_ (N_ / NT_)    // 1024 adj rows per block

typedef __bf16 bf16x8 __attribute__((ext_vector_type(8)));
typedef float floatx16 __attribute__((ext_vector_type(16)));
typedef unsigned int u32;

__device__ inline bf16x8 load_cvt8(const float* __restrict__ p) {
  const float4 u = *(const float4*)p;
  const float4 v = *(const float4*)(p + 4);
  bf16x8 r;
  r[0] = (__bf16)u.x; r[1] = (__bf16)u.y; r[2] = (__bf16)u.z; r[3] = (__bf16)u.w;
  r[4] = (__bf16)v.x; r[5] = (__bf16)v.y; r[6] = (__bf16)v.z; r[7] = (__bf16)v.w;
  return r;
}

// R14 (from R11 best 122.6us): latency pass. (1) W2 staging now fully
// coalesced: 16 float4 loads/thread (lane-skewed stripes), scalar bf16
// scatter into the SAME swizzled-granule LDS image (bit-identical to the
// old 64-scalar-gather version). (2) x gather pipelined 2-deep: chunk body
// (~600cy) + stage-B (~300cy) now covers the ~900cy cold-HBM latency (the
// harness's 256MiB ws poison evicts L2/L3 every iteration, so gathers are
// cold). (3) epilogue uses max(c+b,0)=b+max(c,-b); the b-terms fold into
// one fma after the loop (saves 32 v_add/chunk). Envelope stays (256,2) --
// the only spill-free occupancy point per R2/R5/R7/R8/R9.
__global__ __launch_bounds__(256, 2) void edge_kernel(
    const float* __restrict__ x, const float* __restrict__ adj,
    const float* __restrict__ W1, const float* __restrict__ b1,
    const float* __restrict__ W2, const float* __restrict__ b2,
    const int* __restrict__ ip, float* __restrict__ part)
{
  // sW2: col c = 128 contiguous bf16 (16 granules of 8), granule slot gg^(c&15),
  // rows bit2<->bit3-permuted: granule gg element j holds
  // W2[16*(gg>>1) + 8*(j>>2) + 4*(gg&1) + (j&3)][c].
  __shared__ __align__(16) __bf16 sW2[HID_ * HID_];
  __shared__ __align__(16) float sW1s[DIM_][HID_];   // W1 starter rows, coalesced staged
  __shared__ int   sIdx[ROWS_ + 192];
  __shared__ float sAcc[HID_];
  __shared__ float sB1[HID_];
  __shared__ float sEnder[DIM_];
  __shared__ int   sCnt;

  const int t  = threadIdx.x;
  const int b  = blockIdx.y;
  const int n0 = blockIdx.x * ROWS_;
  const int ii = __ldg(ip);

  const int wave = t >> 6, lane = t & 63;
  const int half = lane >> 5, l31 = lane & 31;
  const int rg = wave >> 1;           // row-group: chunks rg*32, step 64
  const int ch = wave & 1;            // col-half: cols ch*64 .. ch*64+63

  if (t == 0) sCnt = 0;
  if (t < HID_) sAcc[t] = 0.f;
  if (t < DIM_) sEnder[t] = x[((size_t)b * N_ + ii) * DIM_ + t];
  __syncthreads();

  // ---- ballot-based compaction: 1 LDS atomic per wave-iter ----
  #pragma unroll
  for (int r = t; r < ROWS_; r += 256) {
    const bool act = adj[n0 + r] != 0.f;
    const unsigned long long m = __ballot(act);
    int base = 0;
    if (lane == 0) base = atomicAdd(&sCnt, __popcll(m));
    base = __shfl(base, 0);
    if (act) {
      const int pre = __builtin_amdgcn_mbcnt_hi((u32)(m >> 32),
                      __builtin_amdgcn_mbcnt_lo((u32)m, 0));
      sIdx[base + pre] = n0 + r;
    }
  }

  // ---- W1 starter rows -> LDS, fully coalesced ----
  #pragma unroll
  for (int e = t; e < DIM_ * HID_; e += 256) sW1s[e >> 7][e & 127] = W1[e];

  // ---- stage W2^T into LDS: COALESCED float4 loads, bf16 scatter into
  //      XOR-swizzled pi-permuted granules (image identical to R11) ----
  //      thread t, step i2: linear f32 stripe (i2*256 + t)*4 .. +3
  //      -> row = 8*i2 + (t>>5), cols 4*(t&31)+w.  Lane-skew i2 spreads
  //      the LDS scatter across banks (~2-way) while keeping each global
  //      load a contiguous 64B segment per 4-lane group.
  #pragma unroll
  for (int i = 0; i < 16; ++i) {
    const int i2 = (i + (t >> 2)) & 15;
    const int Lbase = (i2 * 256 + t) * 4;
    const float4 v4 = *(const float4*)&W2[Lbase];
    const int row = Lbase >> 7;                       // 8*i2 + (t>>5)
    const int gg  = ((row >> 4) << 1) | ((row >> 2) & 1);
    const int j   = (((row >> 3) & 1) << 2) | (row & 3);
    const int cb0 = Lbase & 127;                      // 4*(t&31)
    #pragma unroll
    for (int w = 0; w < 4; ++w) {
      const float fv = (w == 0) ? v4.x : (w == 1) ? v4.y : (w == 2) ? v4.z : v4.w;
      const int c = cb0 + w;
      sW2[(c << 7) + ((gg ^ (c & 15)) << 3) + j] = (__bf16)fv;
    }
  }

  // ---- cooperative ender-fold: sB1[f] = b1[f] + ender . W1[16:32, f] ----
  if (t < HID_) {
    float s = b1[t];
    #pragma unroll
    for (int k = 0; k < DIM_; ++k) s += sEnder[k] * W1[(DIM_ + k) * HID_ + t];
    sB1[t] = s;
  }

  const float bv0 = b2[ch * 64 + l31], bv1 = b2[ch * 64 + 32 + l31];
  const float nb0 = -bv0, nb1 = -bv1;

  __syncthreads();                       // sIdx/sCnt/sW2/sW1s/sB1 ready
  const int cnt = sCnt;
  const int nch64 = (cnt + 63) >> 6;
  const int end = nch64 * 64;
  for (int p = cnt + t; p < end + 128; p += 256) sIdx[p] = n0;  // pad + 2-deep slack

  // W1^T A-frags from LDS (m=feat=l31+32ft, k=half*8+j)
  bf16x8 w1f[4];
  #pragma unroll
  for (int ft = 0; ft < 4; ++ft) {
    bf16x8 v;
    #pragma unroll
    for (int j = 0; j < 8; ++j) v[j] = (__bf16)sW1s[half * 8 + j][ft * 32 + l31];
    w1f[ft] = v;
  }

  // ---- W2 B-frags for this wave's col-half: read ONCE from swizzled LDS ----
  bf16x8 w2r[16];                        // [s] = col-tile0, [8+s] = col-tile1
  {
    const int c0 = ch * 64 + l31;
    const __bf16* base0 = &sW2[(c0 << 7)];
    const __bf16* base1 = &sW2[((c0 + 32) << 7)];
    #pragma unroll
    for (int s = 0; s < 8; ++s) {
      const int gp = ((s << 1) + half) ^ (c0 & 15);
      w2r[s]     = *(const bf16x8*)(base0 + (gp << 3));
      w2r[8 + s] = *(const bf16x8*)(base1 + (gp << 3));
    }
  }

  // bias delivered via spare-K MFMA (k=0: bf16 hi, k=1: bf16 residual)
  bf16x8 a2f[4], onef;
  #pragma unroll
  for (int j = 0; j < 8; ++j) onef[j] = (__bf16)0.f;
  if (half == 0) { onef[0] = (__bf16)1.f; onef[1] = (__bf16)1.f; }
  #pragma unroll
  for (int ft = 0; ft < 4; ++ft) {
    bf16x8 v;
    #pragma unroll
    for (int j = 0; j < 8; ++j) v[j] = (__bf16)0.f;
    if (half == 0) {
      const float s = sB1[ft * 32 + l31];
      const __bf16 hi = (__bf16)s;
      v[0] = hi;
      v[1] = (__bf16)(s - (float)hi);
    }
    a2f[ft] = v;
  }
  __syncthreads();                       // pad visible

  float sum0 = 0.f, sum1 = 0.f;
  int nfull = 0;
  floatx16 zf;
  #pragma unroll
  for (int r = 0; r < 16; ++r) zf[r] = 0.f;

  // 2-deep gather pipeline (pad guarantees sIdx valid to end+95)
  int cb = rg * 32;
  bf16x8 xf0, xf1;
  {
    const int r0 = sIdx[cb + l31];
    xf0 = load_cvt8(&x[((size_t)b * N_ + r0) * DIM_ + half * 8]);
    const int r1 = sIdx[cb + 64 + l31];
    xf1 = load_cvt8(&x[((size_t)b * N_ + r1) * DIM_ + half * 8]);
  }

  for (; cb < end; cb += 64) {
    const int nrow = sIdx[cb + 128 + l31];           // 2 iters ahead (pad-safe)

    // ---- stage A: h1^T tiles; pi-permutation makes the repack register-local ----
    bf16x8 af[8];                        // stage-B A-frags, k = s*16 + half*8 + j
    #pragma unroll
    for (int ft = 0; ft < 4; ++ft) {
      floatx16 hc = __builtin_amdgcn_mfma_f32_32x32x16_bf16(w1f[ft], xf0, zf, 0, 0, 0);
      hc = __builtin_amdgcn_mfma_f32_32x32x16_bf16(a2f[ft], onef, hc, 0, 0, 0);
      bf16x8 a0, a1;
      #pragma unroll
      for (int j = 0; j < 8; ++j) {
        a0[j] = (__bf16)fmaxf(hc[j],     0.f);
        a1[j] = (__bf16)fmaxf(hc[8 + j], 0.f);
      }
      af[2 * ft]     = a0;
      af[2 * ft + 1] = a1;
    }

    // prefetch gather for iter+2; its waitcnt lands a full chunk later
    const bf16x8 xf2 = load_cvt8(&x[((size_t)b * N_ + nrow) * DIM_ + half * 8]);

    // ---- stage B: 32 rows x 64 cols, K=128; B-frags from REGISTERS ----
    floatx16 c0 = zf, c1 = zf;
    #pragma unroll
    for (int s = 0; s < 8; ++s) {
      c0 = __builtin_amdgcn_mfma_f32_32x32x16_bf16(af[s], w2r[s],     c0, 0, 0, 0);
      c1 = __builtin_amdgcn_mfma_f32_32x32x16_bf16(af[s], w2r[8 + s], c1, 0, 0, 0);
    }

    // ---- epilogue: relu + row-sum; bias deferred via max(c+b,0)=b+max(c,-b) ----
    if (cb + 32 <= cnt) {
      ++nfull;
      #pragma unroll
      for (int r = 0; r < 16; ++r) {
        sum0 += fmaxf(c0[r], nb0);
        sum1 += fmaxf(c1[r], nb1);
      }
    } else {
      #pragma unroll
      for (int r = 0; r < 16; ++r) {
        const int q = cb + (r & 3) + ((r >> 2) << 3) + (half << 2);
        if (q < cnt) {
          sum0 += fmaxf(c0[r] + bv0, 0.f);
          sum1 += fmaxf(c1[r] + bv1, 0.f);
        }
      }
    }
    xf0 = xf1; xf1 = xf2;
  }
  // fold the deferred bias terms: each full chunk contributed 16 rows/half
  const float fn = (float)nfull * 16.f;
  sum0 = fmaf(fn, bv0, sum0);
  sum1 = fmaf(fn, bv1, sum1);

  // fold halves; two waves share each col-half -> LDS atomics
  sum0 += __shfl_xor(sum0, 32);
  sum1 += __shfl_xor(sum1, 32);
  if (half == 0) {
    atomicAdd(&sAcc[ch * 64 + l31],      sum0);
    atomicAdd(&sAcc[ch * 64 + 32 + l31], sum1);
  }
  __syncthreads();
  if (t < HID_) part[((size_t)b * NT_ + blockIdx.x) * HID_ + t] = sAcc[t];
}

// acc = sum partials; h3 = relu(acc@W3+b3); h4 = relu(h3@W4+b4);
// out = [x[:,i,:] | h4] @ W5 + b5   (all fp32, exact)
// R14: 256 threads, K split in half per layer (halves the dependent-load
// latency chain against poison-evicted weights); 144-long output dot split
// 16-ways so all W5 loads issue in one latency wave.
__global__ __launch_bounds__(256) void tail_kernel(
    const float* __restrict__ x, const float* __restrict__ part,
    const float* __restrict__ W3, const float* __restrict__ b3,
    const float* __restrict__ W4, const float* __restrict__ b4,
    const float* __restrict__ W5, const float* __restrict__ b5,
    const int* __restrict__ ip, float* __restrict__ out)
{
  const int b = blockIdx.x, t = threadIdx.x;   // 256 threads
  const int col = t & 127, kh = t >> 7;        // kh in {0,1}: K-half
  __shared__ float s0[HID_], s1[HID_], s2[HID_], se[DIM_];
  __shared__ float sp[2][HID_];
  __shared__ float so[16][DIM_];
  const int ii = __ldg(ip);
  if (t < DIM_) se[t] = x[((size_t)b * N_ + ii) * DIM_ + t];
  if (t < HID_) {
    float a = 0.f;
    #pragma unroll
    for (int p = 0; p < NT_; ++p) a += part[((size_t)b * NT_ + p) * HID_ + t];
    s0[t] = a;
  }
  __syncthreads();
  float v = 0.f;
  #pragma unroll 32
  for (int q = 0; q < 64; ++q) {
    const int k = kh * 64 + q;
    v += s0[k] * W3[k * HID_ + col];
  }
  sp[kh][col] = v;
  __syncthreads();
  if (t < HID_) s1[t] = fmaxf(b3[t] + sp[0][t] + sp[1][t], 0.f);
  __syncthreads();
  float w = 0.f;
  #pragma unroll 32
  for (int q = 0; q < 64; ++q) {
    const int k = kh * 64 + q;
    w += s1[k] * W4[k * HID_ + col];
  }
  sp[kh][col] = w;
  __syncthreads();
  if (t < HID_) s2[t] = fmaxf(b4[t] + sp[0][t] + sp[1][t], 0.f);
  __syncthreads();
  // out = [se | s2] @ W5 + b5 : 144-long dot, split across 16 segments
  {
    const int oc = t & 15, seg = t >> 4;       // 16 segs x 9 k's = 144
    float o = 0.f;
    #pragma unroll
    for (int q = 0; q < 9; ++q) {
      const int kk = seg * 9 + q;
      const float cv = (kk < DIM_) ? se[kk] : s2[kk - DIM_];
      o += cv * W5[kk * DIM_ + oc];
    }
    so[seg][oc] = o;
  }
  __syncthreads();
  if (t < DIM_) {
    float acc = b5[t];
    #pragma unroll
    for (int s = 0; s < 16; ++s) acc += so[s][t];
    out[b * DIM_ + t] = acc;
  }
}

extern "C" void kernel_launch(void* const* d_in, const int* in_sizes, int n_in,
                              void* d_out, int out_size, void* d_ws, size_t ws_size,
                              hipStream_t stream) {
  const float* x   = (const float*)d_in[0];
  const float* adj = (const float*)d_in[1];
  const float* W1  = (const float*)d_in[2];   // W_n2e [32,128]
  const float* b1  = (const float*)d_in[3];
  const float* W2  = (const float*)d_in[4];   // W_e2e [128,128]
  const float* b2  = (const float*)d_in[5];
  const float* W3  = (const float*)d_in[6];   // W_e2n
  const float* b3  = (const float*)d_in[7];
  const float* W4  = (const float*)d_in[8];   // W_n2n
  const float* b4  = (const float*)d_in[9];
  const float* W5  = (const float*)d_in[10];  // W_out [144,16]
  const float* b5  = (const float*)d_in[11];
  const int*   ip  = (const int*)d_in[12];
  float* out  = (float*)d_out;
  float* part = (float*)d_ws;                 // [B, NT_, HID] fp32 partials

  edge_kernel<<<dim3(NT_, B_), 256, 0, stream>>>(x, adj, W1, b1, W2, b2, ip, part);
  tail_kernel<<<B_, 256, 0, stream>>>(x, part, W3, b3, W4, b4, W5, b5, ip, out);
}

// Round 2
// 123.418 us; speedup vs baseline: 1.0627x; 1.0627x over previous
//
#include <hip/hip_runtime.h>
#include <hip/hip_bf16.h>

#define B_    128
#define N_    4096
#define DIM_  16
#define HID_  128
#define NT_   4             // grid.x tiles -> 512 blocks, 2 resident/CU
#define ROWS_ (N_ / NT_)    // 1024 adj rows per block

typedef __bf16 bf16x8 __attribute__((ext_vector_type(8)));
typedef float floatx16 __attribute__((ext_vector_type(16)));
typedef unsigned int u32;

__device__ inline bf16x8 load_cvt8(const float* __restrict__ p) {
  const float4 u = *(const float4*)p;
  const float4 v = *(const float4*)(p + 4);
  bf16x8 r;
  r[0] = (__bf16)u.x; r[1] = (__bf16)u.y; r[2] = (__bf16)u.z; r[3] = (__bf16)u.w;
  r[4] = (__bf16)v.x; r[5] = (__bf16)v.y; r[6] = (__bf16)v.z; r[7] = (__bf16)v.w;
  return r;
}

// R15 = R11 (measured best 122.6us) + ONE change: deferred-bias epilogue
// (max(c+b,0) = b + max(c,-b); b-terms folded by one fma after the loop;
// saves 32 v_add per chunk-iter, +3 VGPRs worst case).
// R14 post-mortem (131.2us, reverted): 2-deep prefetch (+8 VGPR) breached
// the (256,2) spill-free envelope, and the W2 scalar-LDS-scatter staging
// traded L2-resident ~coalesced global loads for 64 ds_write_u16 + addr
// VALU. Both reverted to R11 form. Fusion variants (R12 threadfence, R13
// agent atomics) measured slower previously; two-dispatch graph stands.
__global__ __launch_bounds__(256, 2) void edge_kernel(
    const float* __restrict__ x, const float* __restrict__ adj,
    const float* __restrict__ W1, const float* __restrict__ b1,
    const float* __restrict__ W2, const float* __restrict__ b2,
    const int* __restrict__ ip, float* __restrict__ part)
{
  // sW2: col c = 128 contiguous bf16 (16 granules of 8), granule slot gg^(c&15),
  // rows bit2<->bit3-permuted: granule gg element j holds
  // W2[16*(gg>>1) + 8*(j>>2) + 4*(gg&1) + (j&3)][c].
  __shared__ __align__(16) __bf16 sW2[HID_ * HID_];
  __shared__ __align__(16) float sW1s[DIM_][HID_];   // W1 starter rows, coalesced staged
  __shared__ int   sIdx[ROWS_ + 192];
  __shared__ float sAcc[HID_];
  __shared__ float sB1[HID_];
  __shared__ float sEnder[DIM_];
  __shared__ int   sCnt;

  const int t  = threadIdx.x;
  const int b  = blockIdx.y;
  const int n0 = blockIdx.x * ROWS_;
  const int ii = __ldg(ip);

  const int wave = t >> 6, lane = t & 63;
  const int half = lane >> 5, l31 = lane & 31;
  const int rg = wave >> 1;           // row-group: chunks rg*32, step 64
  const int ch = wave & 1;            // col-half: cols ch*64 .. ch*64+63

  if (t == 0) sCnt = 0;
  if (t < HID_) sAcc[t] = 0.f;
  if (t < DIM_) sEnder[t] = x[((size_t)b * N_ + ii) * DIM_ + t];
  __syncthreads();

  // ---- ballot-based compaction: 1 LDS atomic per wave-iter ----
  #pragma unroll
  for (int r = t; r < ROWS_; r += 256) {
    const bool act = adj[n0 + r] != 0.f;
    const unsigned long long m = __ballot(act);
    int base = 0;
    if (lane == 0) base = atomicAdd(&sCnt, __popcll(m));
    base = __shfl(base, 0);
    if (act) {
      const int pre = __builtin_amdgcn_mbcnt_hi((u32)(m >> 32),
                      __builtin_amdgcn_mbcnt_lo((u32)m, 0));
      sIdx[base + pre] = n0 + r;
    }
  }

  // ---- W1 starter rows -> LDS, fully coalesced ----
  #pragma unroll
  for (int e = t; e < DIM_ * HID_; e += 256) sW1s[e >> 7][e & 127] = W1[e];

  // ---- stage W2^T into LDS, bf16, XOR-swizzled granules, pi-permuted rows ----
  #pragma unroll
  for (int e = 0; e < 8; ++e) {
    const int G = t * 8 + e;            // granule id: c = G>>4, gg = G&15
    const int c = G >> 4, gg = G & 15;
    bf16x8 v;
    #pragma unroll
    for (int j = 0; j < 8; ++j) {
      const int row = ((gg >> 1) << 4) + ((j >> 2) << 3) + ((gg & 1) << 2) + (j & 3);
      v[j] = (__bf16)W2[row * HID_ + c];
    }
    *(bf16x8*)&sW2[(c << 7) + ((gg ^ (c & 15)) << 3)] = v;
  }

  // ---- cooperative ender-fold: sB1[f] = b1[f] + ender . W1[16:32, f] ----
  if (t < HID_) {
    float s = b1[t];
    #pragma unroll
    for (int k = 0; k < DIM_; ++k) s += sEnder[k] * W1[(DIM_ + k) * HID_ + t];
    sB1[t] = s;
  }

  const float bv0 = b2[ch * 64 + l31], bv1 = b2[ch * 64 + 32 + l31];
  const float nb0 = -bv0, nb1 = -bv1;

  __syncthreads();                       // sIdx/sCnt/sW2/sW1s/sB1 ready
  const int cnt = sCnt;
  const int nch64 = (cnt + 63) >> 6;
  const int end = nch64 * 64;
  for (int p = cnt + t; p < end + 128; p += 256) sIdx[p] = n0;  // pad + prefetch slack

  // W1^T A-frags from LDS (m=feat=l31+32ft, k=half*8+j)
  bf16x8 w1f[4];
  #pragma unroll
  for (int ft = 0; ft < 4; ++ft) {
    bf16x8 v;
    #pragma unroll
    for (int j = 0; j < 8; ++j) v[j] = (__bf16)sW1s[half * 8 + j][ft * 32 + l31];
    w1f[ft] = v;
  }

  // ---- W2 B-frags for this wave's col-half: read ONCE from swizzled LDS ----
  bf16x8 w2r[16];                        // [s] = col-tile0, [8+s] = col-tile1
  {
    const int c0 = ch * 64 + l31;
    const __bf16* base0 = &sW2[(c0 << 7)];
    const __bf16* base1 = &sW2[((c0 + 32) << 7)];
    #pragma unroll
    for (int s = 0; s < 8; ++s) {
      const int gp = ((s << 1) + half) ^ (c0 & 15);
      w2r[s]     = *(const bf16x8*)(base0 + (gp << 3));
      w2r[8 + s] = *(const bf16x8*)(base1 + (gp << 3));
    }
  }

  // bias delivered via spare-K MFMA (k=0: bf16 hi, k=1: bf16 residual)
  bf16x8 a2f[4], onef;
  #pragma unroll
  for (int j = 0; j < 8; ++j) onef[j] = (__bf16)0.f;
  if (half == 0) { onef[0] = (__bf16)1.f; onef[1] = (__bf16)1.f; }
  #pragma unroll
  for (int ft = 0; ft < 4; ++ft) {
    bf16x8 v;
    #pragma unroll
    for (int j = 0; j < 8; ++j) v[j] = (__bf16)0.f;
    if (half == 0) {
      const float s = sB1[ft * 32 + l31];
      const __bf16 hi = (__bf16)s;
      v[0] = hi;
      v[1] = (__bf16)(s - (float)hi);
    }
    a2f[ft] = v;
  }
  __syncthreads();                       // pad visible

  float sum0 = 0.f, sum1 = 0.f;
  int nfull = 0;
  floatx16 zf;
  #pragma unroll
  for (int r = 0; r < 16; ++r) zf[r] = 0.f;

  // prefetch first gather (pad guarantees sIdx valid)
  int cb = rg * 32;
  bf16x8 xf;
  {
    const int row = sIdx[cb + l31];
    xf = load_cvt8(&x[((size_t)b * N_ + row) * DIM_ + half * 8]);
  }

  for (; cb < end; cb += 64) {
    const int nrow = sIdx[cb + 64 + l31];            // next iter (pad-safe)

    // ---- stage A: h1^T tiles; pi-permutation makes the repack register-local ----
    bf16x8 af[8];                        // stage-B A-frags, k = s*16 + half*8 + j
    #pragma unroll
    for (int ft = 0; ft < 4; ++ft) {
      floatx16 hc = __builtin_amdgcn_mfma_f32_32x32x16_bf16(w1f[ft], xf, zf, 0, 0, 0);
      hc = __builtin_amdgcn_mfma_f32_32x32x16_bf16(a2f[ft], onef, hc, 0, 0, 0);
      bf16x8 a0, a1;
      #pragma unroll
      for (int j = 0; j < 8; ++j) {
        a0[j] = (__bf16)fmaxf(hc[j],     0.f);
        a1[j] = (__bf16)fmaxf(hc[8 + j], 0.f);
      }
      af[2 * ft]     = a0;
      af[2 * ft + 1] = a1;
    }

    // prefetch next x gather; its waitcnt lands after stage B
    const bf16x8 nxf = load_cvt8(&x[((size_t)b * N_ + nrow) * DIM_ + half * 8]);

    // ---- stage B: 32 rows x 64 cols, K=128; B-frags from REGISTERS ----
    floatx16 c0 = zf, c1 = zf;
    #pragma unroll
    for (int s = 0; s < 8; ++s) {
      c0 = __builtin_amdgcn_mfma_f32_32x32x16_bf16(af[s], w2r[s],     c0, 0, 0, 0);
      c1 = __builtin_amdgcn_mfma_f32_32x32x16_bf16(af[s], w2r[8 + s], c1, 0, 0, 0);
    }

    // ---- epilogue: relu + row-sum; bias deferred via max(c+b,0)=b+max(c,-b) ----
    if (cb + 32 <= cnt) {
      ++nfull;
      #pragma unroll
      for (int r = 0; r < 16; ++r) {
        sum0 += fmaxf(c0[r], nb0);
        sum1 += fmaxf(c1[r], nb1);
      }
    } else {
      #pragma unroll
      for (int r = 0; r < 16; ++r) {
        const int q = cb + (r & 3) + ((r >> 2) << 3) + (half << 2);
        if (q < cnt) {
          sum0 += fmaxf(c0[r] + bv0, 0.f);
          sum1 += fmaxf(c1[r] + bv1, 0.f);
        }
      }
    }
    xf = nxf;
  }
  // fold the deferred bias terms: each full chunk contributed 16 rows/half
  const float fn = (float)nfull * 16.f;
  sum0 = fmaf(fn, bv0, sum0);
  sum1 = fmaf(fn, bv1, sum1);

  // fold halves; two waves share each col-half -> LDS atomics
  sum0 += __shfl_xor(sum0, 32);
  sum1 += __shfl_xor(sum1, 32);
  if (half == 0) {
    atomicAdd(&sAcc[ch * 64 + l31],      sum0);
    atomicAdd(&sAcc[ch * 64 + 32 + l31], sum1);
  }
  __syncthreads();
  if (t < HID_) part[((size_t)b * NT_ + blockIdx.x) * HID_ + t] = sAcc[t];
}

// acc = sum partials; h3 = relu(acc@W3+b3); h4 = relu(h3@W4+b4);
// out = [x[:,i,:] | h4] @ W5 + b5   (all fp32, exact)
__global__ void tail_kernel(
    const float* __restrict__ x, const float* __restrict__ part,
    const float* __restrict__ W3, const float* __restrict__ b3,
    const float* __restrict__ W4, const float* __restrict__ b4,
    const float* __restrict__ W5, const float* __restrict__ b5,
    const int* __restrict__ ip, float* __restrict__ out)
{
  const int b = blockIdx.x, t = threadIdx.x;   // 128 threads
  __shared__ float s0[HID_], s1[HID_], s2[HID_], se[DIM_];
  const int ii = __ldg(ip);
  if (t < DIM_) se[t] = x[((size_t)b * N_ + ii) * DIM_ + t];
  float a = 0.f;
  #pragma unroll
  for (int p = 0; p < NT_; ++p) a += part[((size_t)b * NT_ + p) * HID_ + t];
  s0[t] = a;
  __syncthreads();
  float v = b3[t];
  #pragma unroll 16
  for (int k = 0; k < HID_; ++k) v += s0[k] * W3[k * HID_ + t];
  s1[t] = fmaxf(v, 0.f);
  __syncthreads();
  float w = b4[t];
  #pragma unroll 16
  for (int k = 0; k < HID_; ++k) w += s1[k] * W4[k * HID_ + t];
  s2[t] = fmaxf(w, 0.f);
  __syncthreads();
  if (t < DIM_) {
    float o = b5[t];
    #pragma unroll
    for (int k = 0; k < DIM_; ++k) o += se[k] * W5[k * DIM_ + t];
    #pragma unroll 16
    for (int k = 0; k < HID_; ++k) o += s2[k] * W5[(DIM_ + k) * DIM_ + t];
    out[b * DIM_ + t] = o;
  }
}

extern "C" void kernel_launch(void* const* d_in, const int* in_sizes, int n_in,
                              void* d_out, int out_size, void* d_ws, size_t ws_size,
                              hipStream_t stream) {
  const float* x   = (const float*)d_in[0];
  const float* adj = (const float*)d_in[1];
  const float* W1  = (const float*)d_in[2];   // W_n2e [32,128]
  const float* b1  = (const float*)d_in[3];
  const float* W2  = (const float*)d_in[4];   // W_e2e [128,128]
  const float* b2  = (const float*)d_in[5];
  const float* W3  = (const float*)d_in[6];   // W_e2n
  const float* b3  = (const float*)d_in[7];
  const float* W4  = (const float*)d_in[8];   // W_n2n
  const float* b4  = (const float*)d_in[9];
  const float* W5  = (const float*)d_in[10];  // W_out [144,16]
  const float* b5  = (const float*)d_in[11];
  const int*   ip  = (const int*)d_in[12];
  float* out  = (float*)d_out;
  float* part = (float*)d_ws;                 // [B, NT_, HID] fp32 partials

  edge_kernel<<<dim3(NT_, B_), 256, 0, stream>>>(x, adj, W1, b1, W2, b2, ip, part);
  tail_kernel<<<B_, HID_, 0, stream>>>(x, part, W3, b3, W4, b4, W5, b5, ip, out);
}